// Round 16
// baseline (339.228 us; speedup 1.0000x reference)
//
#include <hip/hip_runtime.h>
#include <hip/hip_bf16.h>
#include <cstdint>
#include <cstddef>

using bf16x8 = __attribute__((ext_vector_type(8))) short;
using f32x4  = __attribute__((ext_vector_type(4))) float;

// ---------------- workspace layout (float offsets) ----------------
// [0,4): 16-B zeros page; bf chunk base = 4
static constexpr size_t PART_OFF = 4194308;
static constexpr size_t WT_OFF   = 16777220;
static constexpr size_t WTR_SH   = (size_t)294912 * 8;   // shorts
static constexpr size_t WTM_SH   = (size_t)73728 * 8;    // shorts
static constexpr size_t M2P_OFF  = WT_OFF + (WTR_SH + WTM_SH) / 2;

__device__ __forceinline__ uint32_t pk2(float a, float b) {
  __hip_bfloat162 h = __float22bfloat162_rn(make_float2(a, b));
  union { __hip_bfloat162 h; uint32_t u; } c; c.h = h;
  return c.u;
}

__device__ __forceinline__ void gld16(const void* g, void* l) {
  __builtin_amdgcn_global_load_lds(
      (const __attribute__((address_space(1))) void*)g,
      (__attribute__((address_space(3))) void*)l, 16, 0, 0);
}

// counted-vmcnt barrier (T4)
#define CBAR(N) do { \
    asm volatile("s_waitcnt vmcnt(" #N ")" ::: "memory"); \
    __builtin_amdgcn_sched_barrier(0); \
    __builtin_amdgcn_s_barrier(); \
    __builtin_amdgcn_sched_barrier(0); } while (0)

// ---------------- weight prep: OIHW f32 -> fragment-major bf16 chunks ----------------
__global__ __launch_bounds__(256) void k_prep_w(
    const float* __restrict__ conv_w, const float* __restrict__ mw1,
    short* __restrict__ wTr, short* __restrict__ wTm, float* __restrict__ zp) {
  __shared__ float sm[16 * 292];
  int t = threadIdx.x;
  int bid = blockIdx.x;
  if (bid == 0 && t < 4) zp[t] = 0.f;
  bool is_m = (bid >= 512);
  int b2 = is_m ? (bid - 512) : bid;
  int kidx = is_m ? (b2 & 7) : (b2 & 31);
  int cog  = is_m ? (b2 >> 3) : (b2 >> 5);
  const float* src = is_m ? mw1 : conv_w;
  short* dst = is_m ? wTm : wTr;
  int CI = is_m ? 256 : 1024;
  int ci0 = kidx * 32;
  int co0 = cog * 16;
  for (int e = t; e < 4608; e += 256) {
    int row = e / 288, pos = e - row * 288;
    sm[row * 292 + pos] = src[((size_t)(co0 + row) * CI + ci0) * 9 + pos];
  }
  __syncthreads();
  for (int e = t; e < 576; e += 256) {
    int tap = e >> 6, kg = (e >> 4) & 3, lr = e & 15;
    float v[8];
#pragma unroll
    for (int j = 0; j < 8; ++j) v[j] = sm[lr * 292 + (kg * 8 + j) * 9 + tap];
    uint4 pk = make_uint4(pk2(v[0], v[1]), pk2(v[2], v[3]),
                          pk2(v[4], v[5]), pk2(v[6], v[7]));
    size_t chunk;
    if (is_m) {
      chunk = (((size_t)kidx * 9 + tap) * 16 + cog) * 64 + kg * 16 + lr;
    } else {
      int nb = cog >> 3, cofrag = cog & 7;
      chunk = ((size_t)(kidx * 2 + nb) * 9 + tap) * 512 + cofrag * 64 + kg * 16 + lr;
    }
    *(uint4*)&dst[chunk * 8] = pk;
  }
}

// ---------------- deform MLP + anchors -> prop ----------------
__global__ __launch_bounds__(256) void k_prop(
    const float* __restrict__ o,
    const float* __restrict__ dw1, const float* __restrict__ db1,
    const float* __restrict__ dw2, const float* __restrict__ db2,
    float* __restrict__ prop) {
  __shared__ float o_lds[4 * 768];
  __shared__ float h_lds[4 * 256];
  int t = threadIdx.x;
  int bid = blockIdx.x;
  int b = bid >> 6;
  int rem = bid & 63;
  int i = rem >> 2;
  int j0 = (rem & 3) * 4;
  const float* obase = o + ((size_t)(b * 16 + i) * 16 + j0) * 768;
  for (int e = t; e < 4 * 768; e += 256) o_lds[e] = obase[e];
  __syncthreads();
  float h0 = 0.f, h1 = 0.f, h2 = 0.f, h3 = 0.f;
  for (int k = 0; k < 768; ++k) {
    float w = dw1[k * 256 + t];
    h0 = fmaf(o_lds[k], w, h0);
    h1 = fmaf(o_lds[768 + k], w, h1);
    h2 = fmaf(o_lds[1536 + k], w, h2);
    h3 = fmaf(o_lds[2304 + k], w, h3);
  }
  float bb = db1[t];
  h_lds[t]        = fmaxf(h0 + bb, 0.f);
  h_lds[256 + t]  = fmaxf(h1 + bb, 0.f);
  h_lds[512 + t]  = fmaxf(h2 + bb, 0.f);
  h_lds[768 + t]  = fmaxf(h3 + bb, 0.f);
  __syncthreads();
  if (t < 32) {
    int pos = t >> 3;
    int c   = t & 7;
    float acc = db2[c];
    const float* hp = h_lds + pos * 256;
    for (int k = 0; k < 256; ++k) acc = fmaf(hp[k], dw2[k * 8 + c], acc);
    int p = c >> 2, q = (c >> 1) & 1, cc = c & 1;
    int row = 2 * i + p;
    int col = 2 * (j0 + pos) + q;
    float anchor = (cc == 0) ? ((float)col * 16.f + 8.f) : ((float)row * 16.f + 8.f);
    prop[((size_t)(b * 32 + row) * 32 + col) * 2 + cc] = anchor + acc;
  }
}

// ---------------- grid sample 4 levels -> bf16 chunks [b][cg128][py32][px32] ------
__global__ __launch_bounds__(256) void k_sample(
    const float* __restrict__ f0, const float* __restrict__ f1,
    const float* __restrict__ f2, const float* __restrict__ f3,
    const float* __restrict__ prop, uint4* __restrict__ bfR) {
  int py = blockIdx.x;
  int l  = blockIdx.y;
  int b  = blockIdx.z;
  int t  = threadIdx.x;
  int xq = t & 31;
  int cq = t >> 5;
  const float* f = (l == 0) ? f0 : (l == 1) ? f1 : (l == 2) ? f2 : f3;
  int fsz = 128 >> l;
  float s = (float)(4 << l);

  size_t pidx = ((size_t)b * 32 + py) * 32 + xq;
  float px = prop[pidx * 2 + 0];
  float pv = prop[pidx * 2 + 1];
  float gx = 2.f * px / s / (float)fsz - 1.f;
  float gy = 2.f * pv / s / (float)fsz - 1.f;
  float x = (gx + 1.f) * 0.5f * (float)(fsz - 1);
  float y = (gy + 1.f) * 0.5f * (float)(fsz - 1);
  float x0f = floorf(x), y0f = floorf(y);
  float wx1 = x - x0f, wy1 = y - y0f;

  int off[4];
  float wgt[4];
#pragma unroll
  for (int cy = 0; cy < 2; ++cy) {
#pragma unroll
    for (int cx = 0; cx < 2; ++cx) {
      float xf = x0f + (float)cx;
      float yf = y0f + (float)cy;
      float w = (cy ? wy1 : (1.f - wy1)) * (cx ? wx1 : (1.f - wx1));
      bool valid = (xf >= 0.f) && (xf <= (float)(fsz - 1)) &&
                   (yf >= 0.f) && (yf <= (float)(fsz - 1));
      int xi = (int)fminf(fmaxf(xf, 0.f), (float)(fsz - 1));
      int yi = (int)fminf(fmaxf(yf, 0.f), (float)(fsz - 1));
      off[cy * 2 + cx] = yi * fsz + xi;
      wgt[cy * 2 + cx] = valid ? w : 0.f;
    }
  }
  const float* fb = f + (size_t)b * 256 * fsz * fsz;
#pragma unroll
  for (int i = 0; i < 4; ++i) {
    int cgl = i * 8 + cq;
    float v[8];
#pragma unroll
    for (int j = 0; j < 8; ++j) {
      const float* fc = fb + (size_t)(cgl * 8 + j) * fsz * fsz;
      v[j] = wgt[0] * fc[off[0]] + wgt[1] * fc[off[1]] +
             wgt[2] * fc[off[2]] + wgt[3] * fc[off[3]];
    }
    bfR[(((size_t)b * 128 + l * 32 + cgl) * 32 + py) * 32 + xq] =
        make_uint4(pk2(v[0], v[1]), pk2(v[2], v[3]),
                   pk2(v[4], v[5]), pk2(v[6], v[7]));
  }
}

// ---------------- mask_feat f32 -> bf16 chunks [b][cg32][y128][x128] ----------------
__global__ __launch_bounds__(256) void k_cvt(const float* __restrict__ mf,
                                             uint4* __restrict__ bfA) {
  int d = blockIdx.x * 256 + threadIdx.x;
  int x = d & 127, y = (d >> 7) & 127, cg = (d >> 14) & 31, b = d >> 19;
  const float* src = mf + (((size_t)(b * 256 + cg * 8)) << 14) + (y << 7) + x;
  float v[8];
#pragma unroll
  for (int j = 0; j < 8; ++j) v[j] = src[(size_t)j << 14];
  bfA[d] = make_uint4(pk2(v[0], v[1]), pk2(v[2], v[3]),
                      pk2(v[4], v[5]), pk2(v[6], v[7]));
}

// ---------------- ROI 3x3 conv (R11): gld16 staging + 2-deep fragment pipeline ----
// 256 blocks x 512 thr; tile 256px(8x32) x 128co x K-split4; 8 waves 4Mx2N
__global__ __launch_bounds__(512, 2) void k_roi_mfma(
    const uint4* __restrict__ bfR, const short* __restrict__ wTr,
    float* __restrict__ part) {
  __shared__ __align__(16) short A_s[2][1408 * 8];
  __shared__ __align__(16) short B_s[4608 * 8];
  int t = threadIdx.x;
  int lane = t & 63, wv = t >> 6, wm = wv >> 1, wn = wv & 1;
  int kg = lane >> 4, lr = lane & 15;
  int bid = blockIdx.x;
  int nb = bid & 1;
  int mi = (bid >> 1) & 31;
  int b = mi >> 2, yt = mi & 3;
  int ks = bid >> 6;

  f32x4 acc[4][4];
#pragma unroll
  for (int m = 0; m < 4; ++m)
#pragma unroll
    for (int n = 0; n < 4; ++n) acc[m][n] = {0.f, 0.f, 0.f, 0.f};

  bf16x8 Af[2][4], Bf[2][4];

  const uint4* aptr[3];
  int astep[3], aldst[3];
  bool aon[3];
#pragma unroll
  for (int i = 0; i < 3; ++i) {
    int wq = wv + 8 * i;
    aon[i] = wq < 22;
    int c = wq * 64 + lane;
    int pxi = c >> 2, slot = c & 3;
    int r = pxi / 34;
    int x = pxi - r * 34 - 1;
    int y = yt * 8 + r - 1;
    int cg4 = slot ^ ((pxi >> 1) & 3);
    bool ok = (r < 10) && (x >= 0) && (x < 32) && (y >= 0) && (y < 32);
    long chunk = ok ? (long)((((b * 128 + ks * 32 + cg4) * 32 + y) * 32) + x) : -1L;
    aptr[i] = bfR + chunk;
    astep[i] = ok ? 4096 : 0;
    aldst[i] = wq * 512;
  }
  const size_t BKC = (size_t)4608 * 8;
  const short* bbase = wTr + ((size_t)(ks * 8) * 2 + nb) * BKC;

#define ROI_ISSUE_A(BUF)                                         \
  {                                                              \
    _Pragma("unroll")                                            \
    for (int i = 0; i < 3; ++i)                                  \
      if (aon[i]) {                                              \
        gld16(aptr[i], &A_s[BUF][aldst[i]]);                     \
        aptr[i] += astep[i];                                     \
      }                                                          \
  }
#define ROI_ISSUE_H1(KC)                                         \
  {                                                              \
    const short* bk = bbase + (size_t)(KC) * 2 * BKC;            \
    _Pragma("unroll")                                            \
    for (int j = 0; j < 5; ++j) {                                \
      int w = wv + 8 * j;                                        \
      gld16(bk + (w * 64 + lane) * 8, &B_s[w * 512]);            \
    }                                                            \
  }
#define ROI_ISSUE_H2(KC)                                         \
  {                                                              \
    const short* bk = bbase + (size_t)(KC) * 2 * BKC;            \
    _Pragma("unroll")                                            \
    for (int j = 0; j < 4; ++j) {                                \
      int w = wv + 8 * j;                                        \
      gld16(bk + (2560 + w * 64 + lane) * 8,                     \
            &B_s[20480 + w * 512]);                              \
    }                                                            \
  }

#define ROI_LOADF(PB, TAP)                                                        \
  {                                                                               \
    int ky = (TAP) / 3, kx = (TAP) - ky * 3;                                      \
    _Pragma("unroll")                                                             \
    for (int n = 0; n < 4; ++n)                                                   \
      Bf[PB][n] = *(const bf16x8*)&B_s[((((TAP) * 8 + wn * 4 + n) * 4 + kg) * 16  \
                                        + lr) * 8];                               \
    _Pragma("unroll")                                                             \
    for (int m = 0; m < 4; ++m) {                                                 \
      int pb = wm * 64 + m * 16;                                                  \
      int px = ((pb >> 5) + ky) * 34 + (pb & 31) + lr + kx;                       \
      Af[PB][m] = *(const bf16x8*)&As[(px * 4 + ((kg ^ (px >> 1)) & 3)) * 8];     \
    }                                                                             \
  }
#define ROI_MMA(PB)                                                               \
  {                                                                               \
    _Pragma("unroll")                                                             \
    for (int m = 0; m < 4; ++m)                                                   \
      _Pragma("unroll")                                                           \
      for (int n = 0; n < 4; ++n)                                                 \
        acc[m][n] = __builtin_amdgcn_mfma_f32_16x16x32_bf16(Af[PB][m], Bf[PB][n], \
                                                            acc[m][n], 0, 0, 0);  \
  }
#define ROI_REGION(T0, T1)                                                        \
  {                                                                               \
    ROI_LOADF(0, T0);                                                             \
    _Pragma("unroll")                                                             \
    for (int tp = (T0); tp < (T1); ++tp) {                                        \
      if (tp + 1 < (T1)) { ROI_LOADF((tp + 1) & 1, tp + 1); }                     \
      ROI_MMA(tp & 1);                                                            \
    }                                                                             \
  }

  ROI_ISSUE_H1(0);
  ROI_ISSUE_A(0);
  __syncthreads();

  for (int kc = 0; kc < 7; ++kc) {
    int buf = kc & 1;
    const short* As = A_s[buf];
    ROI_ISSUE_H2(kc);
    ROI_ISSUE_A(buf ^ 1);
    __builtin_amdgcn_s_setprio(1);
    ROI_REGION(0, 5);
    __builtin_amdgcn_s_setprio(0);
    CBAR(2);
    ROI_ISSUE_H1(kc + 1);
    __builtin_amdgcn_s_setprio(1);
    ROI_REGION(5, 9);
    __builtin_amdgcn_s_setprio(0);
    CBAR(0);
  }
  {
    const short* As = A_s[1];
    ROI_ISSUE_H2(7);
    __builtin_amdgcn_s_setprio(1);
    ROI_REGION(0, 5);
    __builtin_amdgcn_s_setprio(0);
    CBAR(0);
    __builtin_amdgcn_s_setprio(1);
    ROI_REGION(5, 9);
    __builtin_amdgcn_s_setprio(0);
  }
#pragma unroll
  for (int m = 0; m < 4; ++m)
#pragma unroll
    for (int r = 0; r < 4; ++r) {
      int p = wm * 64 + m * 16 + kg * 4 + r;
      int y = yt * 8 + (p >> 5), x = p & 31;
      float* dst = part + (size_t)ks * 2097152 + (((size_t)b * 32 + y) * 32 + x) * 256
                        + nb * 128 + wn * 64 + lr;
#pragma unroll
      for (int n = 0; n < 4; ++n) dst[n * 16] = acc[m][n][r];
    }
}

// ---------------- per-pixel classifier MLP (4 pixels/block) ----------------
__global__ __launch_bounds__(256) void k_mlp(
    const float* __restrict__ part, const float* __restrict__ conv_b,
    const float* __restrict__ cw1, const float* __restrict__ cb1,
    const float* __restrict__ cw2, const float* __restrict__ cb2,
    float* __restrict__ logits) {
  __shared__ float v[1024];
  __shared__ float h[1024];
  int t = threadIdx.x;
  size_t base = (size_t)blockIdx.x * 1024;
  const size_t CH = (size_t)8192 * 256;
  for (int e = t; e < 1024; e += 256) {
    float s = part[base + e] + part[CH + base + e] +
              part[2 * CH + base + e] + part[3 * CH + base + e];
    v[e] = s + conv_b[e & 255];
  }
  __syncthreads();
  float a0 = cb1[t], a1 = a0, a2 = a0, a3 = a0;
  for (int k = 0; k < 256; ++k) {
    float w = cw1[k * 256 + t];
    a0 = fmaf(v[k], w, a0);
    a1 = fmaf(v[256 + k], w, a1);
    a2 = fmaf(v[512 + k], w, a2);
    a3 = fmaf(v[768 + k], w, a3);
  }
  h[t]       = fmaxf(a0, 0.f);
  h[256 + t] = fmaxf(a1, 0.f);
  h[512 + t] = fmaxf(a2, 0.f);
  h[768 + t] = fmaxf(a3, 0.f);
  __syncthreads();
  if (t < 24) {
    int pos = t / 6, c = t - 6 * pos;
    float acc = cb2[c];
    const float* hp = h + pos * 256;
    for (int k = 0; k < 256; ++k) acc = fmaf(hp[k], cw2[k * 6 + c], acc);
    logits[((size_t)blockIdx.x * 4 + pos) * 6 + c] = acc;
  }
}

// ---------------- mask head v9: M8N4 ky-split + hoisted-B long-MFMA schedule ------
// 512 blocks x 512 thr; block = 2 rows x 128 cols x 256 co; waves 2M(row) x 4N(64co)
__global__ __launch_bounds__(512, 2) void k_mask_mfma(
    const uint4* __restrict__ bfA, const short* __restrict__ wTm,
    const float* __restrict__ mb1,
    const float* __restrict__ bn_g, const float* __restrict__ bn_b,
    const float* __restrict__ bn_m, const float* __restrict__ bn_v,
    const float* __restrict__ mw2, float* __restrict__ m2p) {
  __shared__ __align__(16) short A_s[2][1040 * 8];   // 2 x 16640B: [2 rows][130][32ci]
  __shared__ __align__(16) short B_s[2][3072 * 8];   // 2 x 49152B: [3 kx][cog16][kg][lr]
  int t = threadIdx.x;
  int lane = t & 63, wv = t >> 6;
  int wm = wv >> 2, wn = wv & 3;
  int kg = lane >> 4, lr = lane & 15;
  int bid = blockIdx.x;
  int b = bid >> 6, yt = bid & 63;

  f32x4 acc[8][4];
#pragma unroll
  for (int m = 0; m < 8; ++m)
#pragma unroll
    for (int n = 0; n < 4; ++n) acc[m][n] = {0.f, 0.f, 0.f, 0.f};

  int ybase[3], cxoff[3], aldst[3];
  bool aok[3];
#pragma unroll
  for (int j = 0; j < 3; ++j) {
    int c = j * 512 + t;
    bool on = c < 1040;
    int cc = on ? c : 0;
    int pxi = cc >> 2, slot = cc & 3;
    int r = pxi / 130;
    int sx = pxi - r * 130;
    int x = sx - 1;
    int cg4 = slot ^ ((pxi >> 1) & 3);
    aok[j] = on && (x >= 0) && (x < 128);
    ybase[j] = 2 * yt + r - 1;
    cxoff[j] = cg4 * 16384 + x;
    aldst[j] = cc * 8;
  }
  int akc = (b * 32) << 14;

#define MSK_ISSUE_A(BUF, KYV, AKC)                                 \
  {                                                                \
    _Pragma("unroll")                                              \
    for (int j = 0; j < 3; ++j) {                                  \
      int y = ybase[j] + (KYV);                                    \
      bool ok = aok[j] && ((unsigned)y < 128u);                    \
      int off = ok ? ((AKC) + cxoff[j] + y * 128) : -1;            \
      if (j < 2 || t < 16) gld16(bfA + off, &A_s[BUF][aldst[j]]);  \
    }                                                              \
  }
#define MSK_ISSUE_B(BUF, BSRC)                                     \
  {                                                                \
    _Pragma("unroll")                                              \
    for (int j = 0; j < 6; ++j) {                                  \
      int idx = j * 512 + t;                                       \
      gld16((BSRC) + idx * 8, &B_s[BUF][idx * 8]);                 \
    }                                                              \
  }

// hoisted-B schedule: 12 B frags once, A 2-deep by m, 12-MFMA runs
#define MSK_COMPUTE(BUF)                                                          \
  {                                                                               \
    const short* As = A_s[BUF];                                                   \
    const short* Bs = B_s[BUF];                                                   \
    bf16x8 Bf[3][4];                                                              \
    _Pragma("unroll")                                                             \
    for (int kx = 0; kx < 3; ++kx)                                                \
      _Pragma("unroll")                                                           \
      for (int n = 0; n < 4; ++n)                                                 \
        Bf[kx][n] = *(const bf16x8*)&Bs[(((kx * 16 + wn * 4 + n) * 4 + kg) * 16   \
                                         + lr) * 8];                              \
    bf16x8 Afp[2][3];                                                             \
    _Pragma("unroll")                                                             \
    for (int kx = 0; kx < 3; ++kx) {                                              \
      int px = wm * 130 + lr + kx;                                                \
      Afp[0][kx] = *(const bf16x8*)&As[(px * 4 + ((kg ^ (px >> 1)) & 3)) * 8];    \
    }                                                                             \
    _Pragma("unroll")                                                             \
    for (int m = 0; m < 8; ++m) {                                                 \
      if (m + 1 < 8) {                                                            \
        _Pragma("unroll")                                                         \
        for (int kx = 0; kx < 3; ++kx) {                                          \
          int px = wm * 130 + (m + 1) * 16 + lr + kx;                             \
          Afp[(m + 1) & 1][kx] =                                                  \
              *(const bf16x8*)&As[(px * 4 + ((kg ^ (px >> 1)) & 3)) * 8];         \
        }                                                                         \
      }                                                                           \
      _Pragma("unroll")                                                           \
      for (int kx = 0; kx < 3; ++kx)                                              \
        _Pragma("unroll")                                                         \
        for (int n = 0; n < 4; ++n)                                               \
          acc[m][n] = __builtin_amdgcn_mfma_f32_16x16x32_bf16(                    \
              Afp[m & 1][kx], Bf[kx][n], acc[m][n], 0, 0, 0);                     \
    }                                                                             \
  }

  MSK_ISSUE_A(0, 0, akc);
  MSK_ISSUE_B(0, wTm);
  CBAR(0);

  int kyv = 0;
  const short* bnext = wTm + 24576;
  for (int s = 0; s < 24; ++s) {
    int buf = s & 1;
    if (s < 23) {
      int nky = (kyv == 2) ? 0 : kyv + 1;
      int nakc = (kyv == 2) ? akc + 65536 : akc;
      MSK_ISSUE_A(buf ^ 1, nky, nakc);
      MSK_ISSUE_B(buf ^ 1, bnext);
      kyv = nky;
      akc = nakc;
      bnext += 24576;
    }
    __builtin_amdgcn_s_setprio(1);
    MSK_COMPUTE(buf);
    __builtin_amdgcn_s_setprio(0);
    CBAR(0);
  }

  // epilogue: bias + BN + ReLU + 1x1, full 256-co in-block reduction
  float sc[4], sh[4], w2v[4], b1[4];
#pragma unroll
  for (int n = 0; n < 4; ++n) {
    int co = wn * 64 + n * 16 + lr;
    float s = bn_g[co] * rsqrtf(bn_v[co] + 1e-5f);
    sc[n] = s;
    sh[n] = bn_b[co] - bn_m[co] * s;
    b1[n] = mb1[co];
    w2v[n] = mw2[co];
  }
  float* red = (float*)&B_s[0][0];   // [2 wm][128 px][66 pad] f32 = 67584B
#pragma unroll
  for (int m = 0; m < 8; ++m)
#pragma unroll
    for (int r = 0; r < 4; ++r) {
      int px = m * 16 + kg * 4 + r;
      float s = 0.f;
#pragma unroll
      for (int n = 0; n < 4; ++n) {
        float z = fmaf(acc[m][n][r] + b1[n], sc[n], sh[n]);
        s = fmaf(w2v[n], fmaxf(z, 0.f), s);
      }
      red[(wm * 128 + px) * 66 + wn * 16 + lr] = s;
    }
  __syncthreads();
  if (t < 256) {
    float s = 0.f;
#pragma unroll
    for (int q = 0; q < 64; ++q) s += red[t * 66 + q];
    int row = 2 * yt + (t >> 7);
    int col = t & 127;
    m2p[((size_t)b * 128 + row) * 128 + col] = s;
  }
}

// ---------------- resize 130x130 -> 512x512 (interior + mb2) ----------------
__global__ __launch_bounds__(256) void k_resize(const float* __restrict__ m2p,
                                                const float* __restrict__ mb2,
                                                float* __restrict__ masks) {
  int idx = blockIdx.x * 256 + threadIdx.x;
  int b = idx >> 18;
  int rem = idx & 262143;
  int y = rem >> 9;
  int x = rem & 511;
  const float SC = 129.0f / 511.0f;
  float sy = (float)y * SC;
  float sx = (float)x * SC;
  float y0f = floorf(sy), x0f = floorf(sx);
  int y0 = (int)y0f, x0 = (int)x0f;
  int y1 = min(y0 + 1, 129), x1 = min(x0 + 1, 129);
  float wy = sy - y0f, wx = sx - x0f;
  float base = mb2[0];
  const float* p0 = m2p + (size_t)b * 16384;

  auto corner = [&](int yy, int xx) -> float {
    if (yy >= 1 && yy <= 128 && xx >= 1 && xx <= 128)
      return base + p0[(yy - 1) * 128 + (xx - 1)];
    return base;
  };
  float tv = corner(y0, x0) * (1.f - wx) + corner(y0, x1) * wx;
  float bv = corner(y1, x0) * (1.f - wx) + corner(y1, x1) * wx;
  masks[idx] = tv * (1.f - wy) + bv * wy;
}

extern "C" void kernel_launch(void* const* d_in, const int* in_sizes, int n_in,
                              void* d_out, int out_size, void* d_ws, size_t ws_size,
                              hipStream_t stream) {
  (void)in_sizes; (void)n_in; (void)out_size; (void)ws_size;
  const float* f0        = (const float*)d_in[1];
  const float* f1        = (const float*)d_in[2];
  const float* f2        = (const float*)d_in[3];
  const float* f3        = (const float*)d_in[4];
  const float* mask_feat = (const float*)d_in[5];
  const float* o         = (const float*)d_in[6];
  const float* dw1       = (const float*)d_in[7];
  const float* db1       = (const float*)d_in[8];
  const float* dw2       = (const float*)d_in[9];
  const float* db2       = (const float*)d_in[10];
  const float* cw1       = (const float*)d_in[11];
  const float* cb1       = (const float*)d_in[12];
  const float* cw2       = (const float*)d_in[13];
  const float* cb2       = (const float*)d_in[14];
  const float* conv_w    = (const float*)d_in[15];
  const float* conv_b    = (const float*)d_in[16];
  const float* mw1       = (const float*)d_in[17];
  const float* mb1       = (const float*)d_in[18];
  const float* bn_g      = (const float*)d_in[19];
  const float* bn_b      = (const float*)d_in[20];
  const float* bn_m      = (const float*)d_in[21];
  const float* bn_v      = (const float*)d_in[22];
  const float* mw2       = (const float*)d_in[23];
  const float* mb2       = (const float*)d_in[24];

  float* ws   = (float*)d_ws;
  uint4* bf   = (uint4*)(ws + 4);
  float* part = ws + PART_OFF;
  short* wTr  = (short*)(ws + WT_OFF);
  short* wTm  = wTr + WTR_SH;
  float* m2p  = ws + M2P_OFF;

  float* out_prop   = (float*)d_out;
  float* out_logits = out_prop + (size_t)8 * 1024 * 2;
  float* out_masks  = out_logits + (size_t)8 * 1024 * 6;

  hipLaunchKernelGGL(k_prep_w, dim3(640), dim3(256), 0, stream,
                     conv_w, mw1, wTr, wTm, ws);
  hipLaunchKernelGGL(k_prop, dim3(512), dim3(256), 0, stream,
                     o, dw1, db1, dw2, db2, out_prop);
  hipLaunchKernelGGL(k_sample, dim3(32, 4, 8), dim3(256), 0, stream,
                     f0, f1, f2, f3, out_prop, bf);
  hipLaunchKernelGGL(k_roi_mfma, dim3(256), dim3(512), 0, stream,
                     bf, wTr, part);
  hipLaunchKernelGGL(k_mlp, dim3(2048), dim3(256), 0, stream,
                     part, conv_b, cw1, cb1, cw2, cb2, out_logits);
  hipLaunchKernelGGL(k_cvt, dim3(16384), dim3(256), 0, stream,
                     mask_feat, bf);
  hipLaunchKernelGGL(k_mask_mfma, dim3(512), dim3(512), 0, stream,
                     bf, wTm, mb1, bn_g, bn_b, bn_m, bn_v, mw2, m2p);
  hipLaunchKernelGGL(k_resize, dim3(8192), dim3(256), 0, stream,
                     m2p, mb2, out_masks);
}

// Round 17
// 338.931 us; speedup vs baseline: 1.0009x; 1.0009x over previous
//
#include <hip/hip_runtime.h>
#include <hip/hip_bf16.h>
#include <cstdint>
#include <cstddef>

using bf16x8 = __attribute__((ext_vector_type(8))) short;
using f32x4  = __attribute__((ext_vector_type(4))) float;

// ---------------- workspace layout (float offsets) ----------------
// [0,4): 16-B zeros page; bf chunk base = 4
static constexpr size_t PART_OFF = 4194308;
static constexpr size_t WT_OFF   = 16777220;
static constexpr size_t WTR_SH   = (size_t)294912 * 8;   // shorts
static constexpr size_t WTM_SH   = (size_t)73728 * 8;    // shorts
static constexpr size_t M2P_OFF  = WT_OFF + (WTR_SH + WTM_SH) / 2;

__device__ __forceinline__ uint32_t pk2(float a, float b) {
  __hip_bfloat162 h = __float22bfloat162_rn(make_float2(a, b));
  union { __hip_bfloat162 h; uint32_t u; } c; c.h = h;
  return c.u;
}

__device__ __forceinline__ void gld16(const void* g, void* l) {
  __builtin_amdgcn_global_load_lds(
      (const __attribute__((address_space(1))) void*)g,
      (__attribute__((address_space(3))) void*)l, 16, 0, 0);
}

// counted-vmcnt barrier (T4)
#define CBAR(N) do { \
    asm volatile("s_waitcnt vmcnt(" #N ")" ::: "memory"); \
    __builtin_amdgcn_sched_barrier(0); \
    __builtin_amdgcn_s_barrier(); \
    __builtin_amdgcn_sched_barrier(0); } while (0)

// plain phase barrier: reads issued above stay above; MFMAs below stay below
#define PBAR() do { \
    __builtin_amdgcn_sched_barrier(0); \
    __builtin_amdgcn_s_barrier(); \
    __builtin_amdgcn_sched_barrier(0); } while (0)

// ---------------- weight prep: OIHW f32 -> fragment-major bf16 chunks ----------------
__global__ __launch_bounds__(256) void k_prep_w(
    const float* __restrict__ conv_w, const float* __restrict__ mw1,
    short* __restrict__ wTr, short* __restrict__ wTm, float* __restrict__ zp) {
  __shared__ float sm[16 * 292];
  int t = threadIdx.x;
  int bid = blockIdx.x;
  if (bid == 0 && t < 4) zp[t] = 0.f;
  bool is_m = (bid >= 512);
  int b2 = is_m ? (bid - 512) : bid;
  int kidx = is_m ? (b2 & 7) : (b2 & 31);
  int cog  = is_m ? (b2 >> 3) : (b2 >> 5);
  const float* src = is_m ? mw1 : conv_w;
  short* dst = is_m ? wTm : wTr;
  int CI = is_m ? 256 : 1024;
  int ci0 = kidx * 32;
  int co0 = cog * 16;
  for (int e = t; e < 4608; e += 256) {
    int row = e / 288, pos = e - row * 288;
    sm[row * 292 + pos] = src[((size_t)(co0 + row) * CI + ci0) * 9 + pos];
  }
  __syncthreads();
  for (int e = t; e < 576; e += 256) {
    int tap = e >> 6, kg = (e >> 4) & 3, lr = e & 15;
    float v[8];
#pragma unroll
    for (int j = 0; j < 8; ++j) v[j] = sm[lr * 292 + (kg * 8 + j) * 9 + tap];
    uint4 pk = make_uint4(pk2(v[0], v[1]), pk2(v[2], v[3]),
                          pk2(v[4], v[5]), pk2(v[6], v[7]));
    size_t chunk;
    if (is_m) {
      chunk = (((size_t)kidx * 9 + tap) * 16 + cog) * 64 + kg * 16 + lr;
    } else {
      int nb = cog >> 3, cofrag = cog & 7;
      chunk = ((size_t)(kidx * 2 + nb) * 9 + tap) * 512 + cofrag * 64 + kg * 16 + lr;
    }
    *(uint4*)&dst[chunk * 8] = pk;
  }
}

// ---------------- deform MLP + anchors -> prop ----------------
__global__ __launch_bounds__(256) void k_prop(
    const float* __restrict__ o,
    const float* __restrict__ dw1, const float* __restrict__ db1,
    const float* __restrict__ dw2, const float* __restrict__ db2,
    float* __restrict__ prop) {
  __shared__ float o_lds[4 * 768];
  __shared__ float h_lds[4 * 256];
  int t = threadIdx.x;
  int bid = blockIdx.x;
  int b = bid >> 6;
  int rem = bid & 63;
  int i = rem >> 2;
  int j0 = (rem & 3) * 4;
  const float* obase = o + ((size_t)(b * 16 + i) * 16 + j0) * 768;
  for (int e = t; e < 4 * 768; e += 256) o_lds[e] = obase[e];
  __syncthreads();
  float h0 = 0.f, h1 = 0.f, h2 = 0.f, h3 = 0.f;
  for (int k = 0; k < 768; ++k) {
    float w = dw1[k * 256 + t];
    h0 = fmaf(o_lds[k], w, h0);
    h1 = fmaf(o_lds[768 + k], w, h1);
    h2 = fmaf(o_lds[1536 + k], w, h2);
    h3 = fmaf(o_lds[2304 + k], w, h3);
  }
  float bb = db1[t];
  h_lds[t]        = fmaxf(h0 + bb, 0.f);
  h_lds[256 + t]  = fmaxf(h1 + bb, 0.f);
  h_lds[512 + t]  = fmaxf(h2 + bb, 0.f);
  h_lds[768 + t]  = fmaxf(h3 + bb, 0.f);
  __syncthreads();
  if (t < 32) {
    int pos = t >> 3;
    int c   = t & 7;
    float acc = db2[c];
    const float* hp = h_lds + pos * 256;
    for (int k = 0; k < 256; ++k) acc = fmaf(hp[k], dw2[k * 8 + c], acc);
    int p = c >> 2, q = (c >> 1) & 1, cc = c & 1;
    int row = 2 * i + p;
    int col = 2 * (j0 + pos) + q;
    float anchor = (cc == 0) ? ((float)col * 16.f + 8.f) : ((float)row * 16.f + 8.f);
    prop[((size_t)(b * 32 + row) * 32 + col) * 2 + cc] = anchor + acc;
  }
}

// ---------------- grid sample 4 levels -> bf16 chunks [b][cg128][py32][px32] ------
__global__ __launch_bounds__(256) void k_sample(
    const float* __restrict__ f0, const float* __restrict__ f1,
    const float* __restrict__ f2, const float* __restrict__ f3,
    const float* __restrict__ prop, uint4* __restrict__ bfR) {
  int py = blockIdx.x;
  int l  = blockIdx.y;
  int b  = blockIdx.z;
  int t  = threadIdx.x;
  int xq = t & 31;
  int cq = t >> 5;
  const float* f = (l == 0) ? f0 : (l == 1) ? f1 : (l == 2) ? f2 : f3;
  int fsz = 128 >> l;
  float s = (float)(4 << l);

  size_t pidx = ((size_t)b * 32 + py) * 32 + xq;
  float px = prop[pidx * 2 + 0];
  float pv = prop[pidx * 2 + 1];
  float gx = 2.f * px / s / (float)fsz - 1.f;
  float gy = 2.f * pv / s / (float)fsz - 1.f;
  float x = (gx + 1.f) * 0.5f * (float)(fsz - 1);
  float y = (gy + 1.f) * 0.5f * (float)(fsz - 1);
  float x0f = floorf(x), y0f = floorf(y);
  float wx1 = x - x0f, wy1 = y - y0f;

  int off[4];
  float wgt[4];
#pragma unroll
  for (int cy = 0; cy < 2; ++cy) {
#pragma unroll
    for (int cx = 0; cx < 2; ++cx) {
      float xf = x0f + (float)cx;
      float yf = y0f + (float)cy;
      float w = (cy ? wy1 : (1.f - wy1)) * (cx ? wx1 : (1.f - wx1));
      bool valid = (xf >= 0.f) && (xf <= (float)(fsz - 1)) &&
                   (yf >= 0.f) && (yf <= (float)(fsz - 1));
      int xi = (int)fminf(fmaxf(xf, 0.f), (float)(fsz - 1));
      int yi = (int)fminf(fmaxf(yf, 0.f), (float)(fsz - 1));
      off[cy * 2 + cx] = yi * fsz + xi;
      wgt[cy * 2 + cx] = valid ? w : 0.f;
    }
  }
  const float* fb = f + (size_t)b * 256 * fsz * fsz;
#pragma unroll
  for (int i = 0; i < 4; ++i) {
    int cgl = i * 8 + cq;
    float v[8];
#pragma unroll
    for (int j = 0; j < 8; ++j) {
      const float* fc = fb + (size_t)(cgl * 8 + j) * fsz * fsz;
      v[j] = wgt[0] * fc[off[0]] + wgt[1] * fc[off[1]] +
             wgt[2] * fc[off[2]] + wgt[3] * fc[off[3]];
    }
    bfR[(((size_t)b * 128 + l * 32 + cgl) * 32 + py) * 32 + xq] =
        make_uint4(pk2(v[0], v[1]), pk2(v[2], v[3]),
                   pk2(v[4], v[5]), pk2(v[6], v[7]));
  }
}

// ---------------- mask_feat f32 -> bf16 chunks [b][cg32][y128][x128] ----------------
__global__ __launch_bounds__(256) void k_cvt(const float* __restrict__ mf,
                                             uint4* __restrict__ bfA) {
  int d = blockIdx.x * 256 + threadIdx.x;
  int x = d & 127, y = (d >> 7) & 127, cg = (d >> 14) & 31, b = d >> 19;
  const float* src = mf + (((size_t)(b * 256 + cg * 8)) << 14) + (y << 7) + x;
  float v[8];
#pragma unroll
  for (int j = 0; j < 8; ++j) v[j] = src[(size_t)j << 14];
  bfA[d] = make_uint4(pk2(v[0], v[1]), pk2(v[2], v[3]),
                      pk2(v[4], v[5]), pk2(v[6], v[7]));
}

// ---------------- ROI 3x3 conv (R11): gld16 staging + 2-deep fragment pipeline ----
// 256 blocks x 512 thr; tile 256px(8x32) x 128co x K-split4; 8 waves 4Mx2N
__global__ __launch_bounds__(512, 2) void k_roi_mfma(
    const uint4* __restrict__ bfR, const short* __restrict__ wTr,
    float* __restrict__ part) {
  __shared__ __align__(16) short A_s[2][1408 * 8];
  __shared__ __align__(16) short B_s[4608 * 8];
  int t = threadIdx.x;
  int lane = t & 63, wv = t >> 6, wm = wv >> 1, wn = wv & 1;
  int kg = lane >> 4, lr = lane & 15;
  int bid = blockIdx.x;
  int nb = bid & 1;
  int mi = (bid >> 1) & 31;
  int b = mi >> 2, yt = mi & 3;
  int ks = bid >> 6;

  f32x4 acc[4][4];
#pragma unroll
  for (int m = 0; m < 4; ++m)
#pragma unroll
    for (int n = 0; n < 4; ++n) acc[m][n] = {0.f, 0.f, 0.f, 0.f};

  bf16x8 Af[2][4], Bf[2][4];

  const uint4* aptr[3];
  int astep[3], aldst[3];
  bool aon[3];
#pragma unroll
  for (int i = 0; i < 3; ++i) {
    int wq = wv + 8 * i;
    aon[i] = wq < 22;
    int c = wq * 64 + lane;
    int pxi = c >> 2, slot = c & 3;
    int r = pxi / 34;
    int x = pxi - r * 34 - 1;
    int y = yt * 8 + r - 1;
    int cg4 = slot ^ ((pxi >> 1) & 3);
    bool ok = (r < 10) && (x >= 0) && (x < 32) && (y >= 0) && (y < 32);
    long chunk = ok ? (long)((((b * 128 + ks * 32 + cg4) * 32 + y) * 32) + x) : -1L;
    aptr[i] = bfR + chunk;
    astep[i] = ok ? 4096 : 0;
    aldst[i] = wq * 512;
  }
  const size_t BKC = (size_t)4608 * 8;
  const short* bbase = wTr + ((size_t)(ks * 8) * 2 + nb) * BKC;

#define ROI_ISSUE_A(BUF)                                         \
  {                                                              \
    _Pragma("unroll")                                            \
    for (int i = 0; i < 3; ++i)                                  \
      if (aon[i]) {                                              \
        gld16(aptr[i], &A_s[BUF][aldst[i]]);                     \
        aptr[i] += astep[i];                                     \
      }                                                          \
  }
#define ROI_ISSUE_H1(KC)                                         \
  {                                                              \
    const short* bk = bbase + (size_t)(KC) * 2 * BKC;            \
    _Pragma("unroll")                                            \
    for (int j = 0; j < 5; ++j) {                                \
      int w = wv + 8 * j;                                        \
      gld16(bk + (w * 64 + lane) * 8, &B_s[w * 512]);            \
    }                                                            \
  }
#define ROI_ISSUE_H2(KC)                                         \
  {                                                              \
    const short* bk = bbase + (size_t)(KC) * 2 * BKC;            \
    _Pragma("unroll")                                            \
    for (int j = 0; j < 4; ++j) {                                \
      int w = wv + 8 * j;                                        \
      gld16(bk + (2560 + w * 64 + lane) * 8,                     \
            &B_s[20480 + w * 512]);                              \
    }                                                            \
  }

#define ROI_LOADF(PB, TAP)                                                        \
  {                                                                               \
    int ky = (TAP) / 3, kx = (TAP) - ky * 3;                                      \
    _Pragma("unroll")                                                             \
    for (int n = 0; n < 4; ++n)                                                   \
      Bf[PB][n] = *(const bf16x8*)&B_s[((((TAP) * 8 + wn * 4 + n) * 4 + kg) * 16  \
                                        + lr) * 8];                               \
    _Pragma("unroll")                                                             \
    for (int m = 0; m < 4; ++m) {                                                 \
      int pb = wm * 64 + m * 16;                                                  \
      int px = ((pb >> 5) + ky) * 34 + (pb & 31) + lr + kx;                       \
      Af[PB][m] = *(const bf16x8*)&As[(px * 4 + ((kg ^ (px >> 1)) & 3)) * 8];     \
    }                                                                             \
  }
#define ROI_MMA(PB)                                                               \
  {                                                                               \
    _Pragma("unroll")                                                             \
    for (int m = 0; m < 4; ++m)                                                   \
      _Pragma("unroll")                                                           \
      for (int n = 0; n < 4; ++n)                                                 \
        acc[m][n] = __builtin_amdgcn_mfma_f32_16x16x32_bf16(Af[PB][m], Bf[PB][n], \
                                                            acc[m][n], 0, 0, 0);  \
  }
#define ROI_REGION(T0, T1)                                                        \
  {                                                                               \
    ROI_LOADF(0, T0);                                                             \
    _Pragma("unroll")                                                             \
    for (int tp = (T0); tp < (T1); ++tp) {                                        \
      if (tp + 1 < (T1)) { ROI_LOADF((tp + 1) & 1, tp + 1); }                     \
      ROI_MMA(tp & 1);                                                            \
    }                                                                             \
  }

  ROI_ISSUE_H1(0);
  ROI_ISSUE_A(0);
  __syncthreads();

  for (int kc = 0; kc < 7; ++kc) {
    int buf = kc & 1;
    const short* As = A_s[buf];
    ROI_ISSUE_H2(kc);
    ROI_ISSUE_A(buf ^ 1);
    __builtin_amdgcn_s_setprio(1);
    ROI_REGION(0, 5);
    __builtin_amdgcn_s_setprio(0);
    CBAR(2);
    ROI_ISSUE_H1(kc + 1);
    __builtin_amdgcn_s_setprio(1);
    ROI_REGION(5, 9);
    __builtin_amdgcn_s_setprio(0);
    CBAR(0);
  }
  {
    const short* As = A_s[1];
    ROI_ISSUE_H2(7);
    __builtin_amdgcn_s_setprio(1);
    ROI_REGION(0, 5);
    __builtin_amdgcn_s_setprio(0);
    CBAR(0);
    __builtin_amdgcn_s_setprio(1);
    ROI_REGION(5, 9);
    __builtin_amdgcn_s_setprio(0);
  }
#pragma unroll
  for (int m = 0; m < 4; ++m)
#pragma unroll
    for (int r = 0; r < 4; ++r) {
      int p = wm * 64 + m * 16 + kg * 4 + r;
      int y = yt * 8 + (p >> 5), x = p & 31;
      float* dst = part + (size_t)ks * 2097152 + (((size_t)b * 32 + y) * 32 + x) * 256
                        + nb * 128 + wn * 64 + lr;
#pragma unroll
      for (int n = 0; n < 4; ++n) dst[n * 16] = acc[m][n][r];
    }
}

// ---------------- per-pixel classifier MLP (4 pixels/block) ----------------
__global__ __launch_bounds__(256) void k_mlp(
    const float* __restrict__ part, const float* __restrict__ conv_b,
    const float* __restrict__ cw1, const float* __restrict__ cb1,
    const float* __restrict__ cw2, const float* __restrict__ cb2,
    float* __restrict__ logits) {
  __shared__ float v[1024];
  __shared__ float h[1024];
  int t = threadIdx.x;
  size_t base = (size_t)blockIdx.x * 1024;
  const size_t CH = (size_t)8192 * 256;
  for (int e = t; e < 1024; e += 256) {
    float s = part[base + e] + part[CH + base + e] +
              part[2 * CH + base + e] + part[3 * CH + base + e];
    v[e] = s + conv_b[e & 255];
  }
  __syncthreads();
  float a0 = cb1[t], a1 = a0, a2 = a0, a3 = a0;
  for (int k = 0; k < 256; ++k) {
    float w = cw1[k * 256 + t];
    a0 = fmaf(v[k], w, a0);
    a1 = fmaf(v[256 + k], w, a1);
    a2 = fmaf(v[512 + k], w, a2);
    a3 = fmaf(v[768 + k], w, a3);
  }
  h[t]       = fmaxf(a0, 0.f);
  h[256 + t] = fmaxf(a1, 0.f);
  h[512 + t] = fmaxf(a2, 0.f);
  h[768 + t] = fmaxf(a3, 0.f);
  __syncthreads();
  if (t < 24) {
    int pos = t / 6, c = t - 6 * pos;
    float acc = cb2[c];
    const float* hp = h + pos * 256;
    for (int k = 0; k < 256; ++k) acc = fmaf(hp[k], cw2[k * 6 + c], acc);
    logits[((size_t)blockIdx.x * 4 + pos) * 6 + c] = acc;
  }
}

// ---------------- mask head v11: M8N4 ky-split + kx-phase discipline ----------------
// 512 blocks x 512 thr; block = 2 rows x 128 cols x 256 co; waves 2M(row) x 4N(64co)
__global__ __launch_bounds__(512, 2) void k_mask_mfma(
    const uint4* __restrict__ bfA, const short* __restrict__ wTm,
    const float* __restrict__ mb1,
    const float* __restrict__ bn_g, const float* __restrict__ bn_b,
    const float* __restrict__ bn_m, const float* __restrict__ bn_v,
    const float* __restrict__ mw2, float* __restrict__ m2p) {
  __shared__ __align__(16) short A_s[2][1040 * 8];   // 2 x 16640B: [2 rows][130][32ci]
  __shared__ __align__(16) short B_s[2][3072 * 8];   // 2 x 49152B: [3 kx][cog16][kg][lr]
  int t = threadIdx.x;
  int lane = t & 63, wv = t >> 6;
  int wm = wv >> 2, wn = wv & 3;
  int kg = lane >> 4, lr = lane & 15;
  int bid = blockIdx.x;
  int b = bid >> 6, yt = bid & 63;

  f32x4 acc[8][4];
#pragma unroll
  for (int m = 0; m < 8; ++m)
#pragma unroll
    for (int n = 0; n < 4; ++n) acc[m][n] = {0.f, 0.f, 0.f, 0.f};

  int ybase[3], cxoff[3], aldst[3];
  bool aok[3];
#pragma unroll
  for (int j = 0; j < 3; ++j) {
    int c = j * 512 + t;
    bool on = c < 1040;
    int cc = on ? c : 0;
    int pxi = cc >> 2, slot = cc & 3;
    int r = pxi / 130;
    int sx = pxi - r * 130;
    int x = sx - 1;
    int cg4 = slot ^ ((pxi >> 1) & 3);
    aok[j] = on && (x >= 0) && (x < 128);
    ybase[j] = 2 * yt + r - 1;
    cxoff[j] = cg4 * 16384 + x;
    aldst[j] = cc * 8;
  }
  int akc = (b * 32) << 14;

#define MSK_ISSUE_A(BUF, KYV, AKC)                                 \
  {                                                                \
    _Pragma("unroll")                                              \
    for (int j = 0; j < 3; ++j) {                                  \
      int y = ybase[j] + (KYV);                                    \
      bool ok = aok[j] && ((unsigned)y < 128u);                    \
      int off = ok ? ((AKC) + cxoff[j] + y * 128) : -1;            \
      if (j < 2 || t < 16) gld16(bfA + off, &A_s[BUF][aldst[j]]);  \
    }                                                              \
  }
#define MSK_ISSUE_B(BUF, BSRC)                                     \
  {                                                                \
    _Pragma("unroll")                                              \
    for (int j = 0; j < 6; ++j) {                                  \
      int idx = j * 512 + t;                                       \
      gld16((BSRC) + idx * 8, &B_s[BUF][idx * 8]);                 \
    }                                                              \
  }

// one kx-phase: 12 reads -> barrier -> 32 pure MFMAs
#define MSK_PHASE(BUF, KX)                                                        \
  {                                                                               \
    const short* As = A_s[BUF];                                                   \
    const short* Bs = B_s[BUF];                                                   \
    bf16x8 Bf[4];                                                                 \
    _Pragma("unroll")                                                             \
    for (int n = 0; n < 4; ++n)                                                   \
      Bf[n] = *(const bf16x8*)&Bs[((((KX) * 16 + wn * 4 + n) * 4 + kg) * 16       \
                                   + lr) * 8];                                    \
    bf16x8 Am[8];                                                                 \
    _Pragma("unroll")                                                             \
    for (int m = 0; m < 8; ++m) {                                                 \
      int px = wm * 130 + m * 16 + lr + (KX);                                     \
      Am[m] = *(const bf16x8*)&As[(px * 4 + ((kg ^ (px >> 1)) & 3)) * 8];         \
    }                                                                             \
    PBAR();                                                                       \
    __builtin_amdgcn_s_setprio(1);                                                \
    _Pragma("unroll")                                                             \
    for (int m = 0; m < 8; ++m)                                                   \
      _Pragma("unroll")                                                           \
      for (int n = 0; n < 4; ++n)                                                 \
        acc[m][n] = __builtin_amdgcn_mfma_f32_16x16x32_bf16(Am[m], Bf[n],         \
                                                            acc[m][n], 0, 0, 0);  \
    __builtin_amdgcn_s_setprio(0);                                                \
  }

  MSK_ISSUE_A(0, 0, akc);
  MSK_ISSUE_B(0, wTm);
  CBAR(0);

  int kyv = 0;
  const short* bnext = wTm + 24576;
  for (int s = 0; s < 24; ++s) {
    int buf = s & 1;
    if (s < 23) {
      int nky = (kyv == 2) ? 0 : kyv + 1;
      int nakc = (kyv == 2) ? akc + 65536 : akc;
      MSK_ISSUE_A(buf ^ 1, nky, nakc);
      MSK_ISSUE_B(buf ^ 1, bnext);
      kyv = nky;
      akc = nakc;
      bnext += 24576;
    }
    MSK_PHASE(buf, 0);
    MSK_PHASE(buf, 1);
    MSK_PHASE(buf, 2);
    CBAR(0);
  }

  // epilogue: bias + BN + ReLU + 1x1, full 256-co in-block reduction
  float sc[4], sh[4], w2v[4], b1[4];
#pragma unroll
  for (int n = 0; n < 4; ++n) {
    int co = wn * 64 + n * 16 + lr;
    float s = bn_g[co] * rsqrtf(bn_v[co] + 1e-5f);
    sc[n] = s;
    sh[n] = bn_b[co] - bn_m[co] * s;
    b1[n] = mb1[co];
    w2v[n] = mw2[co];
  }
  float* red = (float*)&B_s[0][0];   // [2 wm][128 px][66 pad] f32 = 67584B
#pragma unroll
  for (int m = 0; m < 8; ++m)
#pragma unroll
    for (int r = 0; r < 4; ++r) {
      int px = m * 16 + kg * 4 + r;
      float s = 0.f;
#pragma unroll
      for (int n = 0; n < 4; ++n) {
        float z = fmaf(acc[m][n][r] + b1[n], sc[n], sh[n]);
        s = fmaf(w2v[n], fmaxf(z, 0.f), s);
      }
      red[(wm * 128 + px) * 66 + wn * 16 + lr] = s;
    }
  __syncthreads();
  if (t < 256) {
    float s = 0.f;
#pragma unroll
    for (int q = 0; q < 64; ++q) s += red[t * 66 + q];
    int row = 2 * yt + (t >> 7);
    int col = t & 127;
    m2p[((size_t)b * 128 + row) * 128 + col] = s;
  }
}

// ---------------- resize 130x130 -> 512x512 (interior + mb2) ----------------
__global__ __launch_bounds__(256) void k_resize(const float* __restrict__ m2p,
                                                const float* __restrict__ mb2,
                                                float* __restrict__ masks) {
  int idx = blockIdx.x * 256 + threadIdx.x;
  int b = idx >> 18;
  int rem = idx & 262143;
  int y = rem >> 9;
  int x = rem & 511;
  const float SC = 129.0f / 511.0f;
  float sy = (float)y * SC;
  float sx = (float)x * SC;
  float y0f = floorf(sy), x0f = floorf(sx);
  int y0 = (int)y0f, x0 = (int)x0f;
  int y1 = min(y0 + 1, 129), x1 = min(x0 + 1, 129);
  float wy = sy - y0f, wx = sx - x0f;
  float base = mb2[0];
  const float* p0 = m2p + (size_t)b * 16384;

  auto corner = [&](int yy, int xx) -> float {
    if (yy >= 1 && yy <= 128 && xx >= 1 && xx <= 128)
      return base + p0[(yy - 1) * 128 + (xx - 1)];
    return base;
  };
  float tv = corner(y0, x0) * (1.f - wx) + corner(y0, x1) * wx;
  float bv = corner(y1, x0) * (1.f - wx) + corner(y1, x1) * wx;
  masks[idx] = tv * (1.f - wy) + bv * wy;
}

extern "C" void kernel_launch(void* const* d_in, const int* in_sizes, int n_in,
                              void* d_out, int out_size, void* d_ws, size_t ws_size,
                              hipStream_t stream) {
  (void)in_sizes; (void)n_in; (void)out_size; (void)ws_size;
  const float* f0        = (const float*)d_in[1];
  const float* f1        = (const float*)d_in[2];
  const float* f2        = (const float*)d_in[3];
  const float* f3        = (const float*)d_in[4];
  const float* mask_feat = (const float*)d_in[5];
  const float* o         = (const float*)d_in[6];
  const float* dw1       = (const float*)d_in[7];
  const float* db1       = (const float*)d_in[8];
  const float* dw2       = (const float*)d_in[9];
  const float* db2       = (const float*)d_in[10];
  const float* cw1       = (const float*)d_in[11];
  const float* cb1       = (const float*)d_in[12];
  const float* cw2       = (const float*)d_in[13];
  const float* cb2       = (const float*)d_in[14];
  const float* conv_w    = (const float*)d_in[15];
  const float* conv_b    = (const float*)d_in[16];
  const float* mw1       = (const float*)d_in[17];
  const float* mb1       = (const float*)d_in[18];
  const float* bn_g      = (const float*)d_in[19];
  const float* bn_b      = (const float*)d_in[20];
  const float* bn_m      = (const float*)d_in[21];
  const float* bn_v      = (const float*)d_in[22];
  const float* mw2       = (const float*)d_in[23];
  const float* mb2       = (const float*)d_in[24];

  float* ws   = (float*)d_ws;
  uint4* bf   = (uint4*)(ws + 4);
  float* part = ws + PART_OFF;
  short* wTr  = (short*)(ws + WT_OFF);
  short* wTm  = wTr + WTR_SH;
  float* m2p  = ws + M2P_OFF;

  float* out_prop   = (float*)d_out;
  float* out_logits = out_prop + (size_t)8 * 1024 * 2;
  float* out_masks  = out_logits + (size_t)8 * 1024 * 6;

  hipLaunchKernelGGL(k_prep_w, dim3(640), dim3(256), 0, stream,
                     conv_w, mw1, wTr, wTm, ws);
  hipLaunchKernelGGL(k_prop, dim3(512), dim3(256), 0, stream,
                     o, dw1, db1, dw2, db2, out_prop);
  hipLaunchKernelGGL(k_sample, dim3(32, 4, 8), dim3(256), 0, stream,
                     f0, f1, f2, f3, out_prop, bf);
  hipLaunchKernelGGL(k_roi_mfma, dim3(256), dim3(512), 0, stream,
                     bf, wTr, part);
  hipLaunchKernelGGL(k_mlp, dim3(2048), dim3(256), 0, stream,
                     part, conv_b, cw1, cb1, cw2, cb2, out_logits);
  hipLaunchKernelGGL(k_cvt, dim3(16384), dim3(256), 0, stream,
                     mask_feat, bf);
  hipLaunchKernelGGL(k_mask_mfma, dim3(512), dim3(512), 0, stream,
                     bf, wTm, mb1, bn_g, bn_b, bn_m, bn_v, mw2, m2p);
  hipLaunchKernelGGL(k_resize, dim3(8192), dim3(256), 0, stream,
                     m2p, mb2, out_masks);
}

// Round 18
// 331.321 us; speedup vs baseline: 1.0239x; 1.0230x over previous
//
#include <hip/hip_runtime.h>
#include <hip/hip_bf16.h>
#include <cstdint>
#include <cstddef>

using bf16x8 = __attribute__((ext_vector_type(8))) short;
using f32x4  = __attribute__((ext_vector_type(4))) float;

// ---------------- workspace layout (float offsets) ----------------
// [0,4): 16-B zeros page; bf chunk base = 4
static constexpr size_t PART_OFF = 4194308;
static constexpr size_t WT_OFF   = 16777220;
static constexpr size_t WTR_SH   = (size_t)294912 * 8;   // shorts
static constexpr size_t WTM_SH   = (size_t)73728 * 8;    // shorts
static constexpr size_t M2P_OFF  = WT_OFF + (WTR_SH + WTM_SH) / 2;

__device__ __forceinline__ uint32_t pk2(float a, float b) {
  __hip_bfloat162 h = __float22bfloat162_rn(make_float2(a, b));
  union { __hip_bfloat162 h; uint32_t u; } c; c.h = h;
  return c.u;
}

__device__ __forceinline__ void gld16(const void* g, void* l) {
  __builtin_amdgcn_global_load_lds(
      (const __attribute__((address_space(1))) void*)g,
      (__attribute__((address_space(3))) void*)l, 16, 0, 0);
}

// counted-vmcnt barrier (T4)
#define CBAR(N) do { \
    asm volatile("s_waitcnt vmcnt(" #N ")" ::: "memory"); \
    __builtin_amdgcn_sched_barrier(0); \
    __builtin_amdgcn_s_barrier(); \
    __builtin_amdgcn_sched_barrier(0); } while (0)

// ---------------- weight prep: OIHW f32 -> fragment-major bf16 chunks ----------------
__global__ __launch_bounds__(256) void k_prep_w(
    const float* __restrict__ conv_w, const float* __restrict__ mw1,
    short* __restrict__ wTr, short* __restrict__ wTm, float* __restrict__ zp) {
  __shared__ float sm[16 * 292];
  int t = threadIdx.x;
  int bid = blockIdx.x;
  if (bid == 0 && t < 4) zp[t] = 0.f;
  bool is_m = (bid >= 512);
  int b2 = is_m ? (bid - 512) : bid;
  int kidx = is_m ? (b2 & 7) : (b2 & 31);
  int cog  = is_m ? (b2 >> 3) : (b2 >> 5);
  const float* src = is_m ? mw1 : conv_w;
  short* dst = is_m ? wTm : wTr;
  int CI = is_m ? 256 : 1024;
  int ci0 = kidx * 32;
  int co0 = cog * 16;
  for (int e = t; e < 4608; e += 256) {
    int row = e / 288, pos = e - row * 288;
    sm[row * 292 + pos] = src[((size_t)(co0 + row) * CI + ci0) * 9 + pos];
  }
  __syncthreads();
  for (int e = t; e < 576; e += 256) {
    int tap = e >> 6, kg = (e >> 4) & 3, lr = e & 15;
    float v[8];
#pragma unroll
    for (int j = 0; j < 8; ++j) v[j] = sm[lr * 292 + (kg * 8 + j) * 9 + tap];
    uint4 pk = make_uint4(pk2(v[0], v[1]), pk2(v[2], v[3]),
                          pk2(v[4], v[5]), pk2(v[6], v[7]));
    size_t chunk;
    if (is_m) {
      chunk = (((size_t)kidx * 9 + tap) * 16 + cog) * 64 + kg * 16 + lr;
    } else {
      int nb = cog >> 3, cofrag = cog & 7;
      chunk = ((size_t)(kidx * 2 + nb) * 9 + tap) * 512 + cofrag * 64 + kg * 16 + lr;
    }
    *(uint4*)&dst[chunk * 8] = pk;
  }
}

// ---------------- deform MLP + anchors -> prop ----------------
__global__ __launch_bounds__(256) void k_prop(
    const float* __restrict__ o,
    const float* __restrict__ dw1, const float* __restrict__ db1,
    const float* __restrict__ dw2, const float* __restrict__ db2,
    float* __restrict__ prop) {
  __shared__ float o_lds[4 * 768];
  __shared__ float h_lds[4 * 256];
  int t = threadIdx.x;
  int bid = blockIdx.x;
  int b = bid >> 6;
  int rem = bid & 63;
  int i = rem >> 2;
  int j0 = (rem & 3) * 4;
  const float* obase = o + ((size_t)(b * 16 + i) * 16 + j0) * 768;
  for (int e = t; e < 4 * 768; e += 256) o_lds[e] = obase[e];
  __syncthreads();
  float h0 = 0.f, h1 = 0.f, h2 = 0.f, h3 = 0.f;
  for (int k = 0; k < 768; ++k) {
    float w = dw1[k * 256 + t];
    h0 = fmaf(o_lds[k], w, h0);
    h1 = fmaf(o_lds[768 + k], w, h1);
    h2 = fmaf(o_lds[1536 + k], w, h2);
    h3 = fmaf(o_lds[2304 + k], w, h3);
  }
  float bb = db1[t];
  h_lds[t]        = fmaxf(h0 + bb, 0.f);
  h_lds[256 + t]  = fmaxf(h1 + bb, 0.f);
  h_lds[512 + t]  = fmaxf(h2 + bb, 0.f);
  h_lds[768 + t]  = fmaxf(h3 + bb, 0.f);
  __syncthreads();
  if (t < 32) {
    int pos = t >> 3;
    int c   = t & 7;
    float acc = db2[c];
    const float* hp = h_lds + pos * 256;
    for (int k = 0; k < 256; ++k) acc = fmaf(hp[k], dw2[k * 8 + c], acc);
    int p = c >> 2, q = (c >> 1) & 1, cc = c & 1;
    int row = 2 * i + p;
    int col = 2 * (j0 + pos) + q;
    float anchor = (cc == 0) ? ((float)col * 16.f + 8.f) : ((float)row * 16.f + 8.f);
    prop[((size_t)(b * 32 + row) * 32 + col) * 2 + cc] = anchor + acc;
  }
}

// ---------------- grid sample 4 levels -> bf16 chunks [b][cg128][py32][px32] ------
__global__ __launch_bounds__(256) void k_sample(
    const float* __restrict__ f0, const float* __restrict__ f1,
    const float* __restrict__ f2, const float* __restrict__ f3,
    const float* __restrict__ prop, uint4* __restrict__ bfR) {
  int py = blockIdx.x;
  int l  = blockIdx.y;
  int b  = blockIdx.z;
  int t  = threadIdx.x;
  int xq = t & 31;
  int cq = t >> 5;
  const float* f = (l == 0) ? f0 : (l == 1) ? f1 : (l == 2) ? f2 : f3;
  int fsz = 128 >> l;
  float s = (float)(4 << l);

  size_t pidx = ((size_t)b * 32 + py) * 32 + xq;
  float px = prop[pidx * 2 + 0];
  float pv = prop[pidx * 2 + 1];
  float gx = 2.f * px / s / (float)fsz - 1.f;
  float gy = 2.f * pv / s / (float)fsz - 1.f;
  float x = (gx + 1.f) * 0.5f * (float)(fsz - 1);
  float y = (gy + 1.f) * 0.5f * (float)(fsz - 1);
  float x0f = floorf(x), y0f = floorf(y);
  float wx1 = x - x0f, wy1 = y - y0f;

  int off[4];
  float wgt[4];
#pragma unroll
  for (int cy = 0; cy < 2; ++cy) {
#pragma unroll
    for (int cx = 0; cx < 2; ++cx) {
      float xf = x0f + (float)cx;
      float yf = y0f + (float)cy;
      float w = (cy ? wy1 : (1.f - wy1)) * (cx ? wx1 : (1.f - wx1));
      bool valid = (xf >= 0.f) && (xf <= (float)(fsz - 1)) &&
                   (yf >= 0.f) && (yf <= (float)(fsz - 1));
      int xi = (int)fminf(fmaxf(xf, 0.f), (float)(fsz - 1));
      int yi = (int)fminf(fmaxf(yf, 0.f), (float)(fsz - 1));
      off[cy * 2 + cx] = yi * fsz + xi;
      wgt[cy * 2 + cx] = valid ? w : 0.f;
    }
  }
  const float* fb = f + (size_t)b * 256 * fsz * fsz;
#pragma unroll
  for (int i = 0; i < 4; ++i) {
    int cgl = i * 8 + cq;
    float v[8];
#pragma unroll
    for (int j = 0; j < 8; ++j) {
      const float* fc = fb + (size_t)(cgl * 8 + j) * fsz * fsz;
      v[j] = wgt[0] * fc[off[0]] + wgt[1] * fc[off[1]] +
             wgt[2] * fc[off[2]] + wgt[3] * fc[off[3]];
    }
    bfR[(((size_t)b * 128 + l * 32 + cgl) * 32 + py) * 32 + xq] =
        make_uint4(pk2(v[0], v[1]), pk2(v[2], v[3]),
                   pk2(v[4], v[5]), pk2(v[6], v[7]));
  }
}

// ---------------- mask_feat f32 -> bf16 chunks [b][cg32][y128][x128] ----------------
__global__ __launch_bounds__(256) void k_cvt(const float* __restrict__ mf,
                                             uint4* __restrict__ bfA) {
  int d = blockIdx.x * 256 + threadIdx.x;
  int x = d & 127, y = (d >> 7) & 127, cg = (d >> 14) & 31, b = d >> 19;
  const float* src = mf + (((size_t)(b * 256 + cg * 8)) << 14) + (y << 7) + x;
  float v[8];
#pragma unroll
  for (int j = 0; j < 8; ++j) v[j] = src[(size_t)j << 14];
  bfA[d] = make_uint4(pk2(v[0], v[1]), pk2(v[2], v[3]),
                      pk2(v[4], v[5]), pk2(v[6], v[7]));
}

// ---------------- ROI 3x3 conv (R11): gld16 staging + 2-deep fragment pipeline ----
// 256 blocks x 512 thr; tile 256px(8x32) x 128co x K-split4; 8 waves 4Mx2N
__global__ __launch_bounds__(512, 2) void k_roi_mfma(
    const uint4* __restrict__ bfR, const short* __restrict__ wTr,
    float* __restrict__ part) {
  __shared__ __align__(16) short A_s[2][1408 * 8];
  __shared__ __align__(16) short B_s[4608 * 8];
  int t = threadIdx.x;
  int lane = t & 63, wv = t >> 6, wm = wv >> 1, wn = wv & 1;
  int kg = lane >> 4, lr = lane & 15;
  int bid = blockIdx.x;
  int nb = bid & 1;
  int mi = (bid >> 1) & 31;
  int b = mi >> 2, yt = mi & 3;
  int ks = bid >> 6;

  f32x4 acc[4][4];
#pragma unroll
  for (int m = 0; m < 4; ++m)
#pragma unroll
    for (int n = 0; n < 4; ++n) acc[m][n] = {0.f, 0.f, 0.f, 0.f};

  bf16x8 Af[2][4], Bf[2][4];

  const uint4* aptr[3];
  int astep[3], aldst[3];
  bool aon[3];
#pragma unroll
  for (int i = 0; i < 3; ++i) {
    int wq = wv + 8 * i;
    aon[i] = wq < 22;
    int c = wq * 64 + lane;
    int pxi = c >> 2, slot = c & 3;
    int r = pxi / 34;
    int x = pxi - r * 34 - 1;
    int y = yt * 8 + r - 1;
    int cg4 = slot ^ ((pxi >> 1) & 3);
    bool ok = (r < 10) && (x >= 0) && (x < 32) && (y >= 0) && (y < 32);
    long chunk = ok ? (long)((((b * 128 + ks * 32 + cg4) * 32 + y) * 32) + x) : -1L;
    aptr[i] = bfR + chunk;
    astep[i] = ok ? 4096 : 0;
    aldst[i] = wq * 512;
  }
  const size_t BKC = (size_t)4608 * 8;
  const short* bbase = wTr + ((size_t)(ks * 8) * 2 + nb) * BKC;

#define ROI_ISSUE_A(BUF)                                         \
  {                                                              \
    _Pragma("unroll")                                            \
    for (int i = 0; i < 3; ++i)                                  \
      if (aon[i]) {                                              \
        gld16(aptr[i], &A_s[BUF][aldst[i]]);                     \
        aptr[i] += astep[i];                                     \
      }                                                          \
  }
#define ROI_ISSUE_H1(KC)                                         \
  {                                                              \
    const short* bk = bbase + (size_t)(KC) * 2 * BKC;            \
    _Pragma("unroll")                                            \
    for (int j = 0; j < 5; ++j) {                                \
      int w = wv + 8 * j;                                        \
      gld16(bk + (w * 64 + lane) * 8, &B_s[w * 512]);            \
    }                                                            \
  }
#define ROI_ISSUE_H2(KC)                                         \
  {                                                              \
    const short* bk = bbase + (size_t)(KC) * 2 * BKC;            \
    _Pragma("unroll")                                            \
    for (int j = 0; j < 4; ++j) {                                \
      int w = wv + 8 * j;                                        \
      gld16(bk + (2560 + w * 64 + lane) * 8,                     \
            &B_s[20480 + w * 512]);                              \
    }                                                            \
  }

#define ROI_LOADF(PB, TAP)                                                        \
  {                                                                               \
    int ky = (TAP) / 3, kx = (TAP) - ky * 3;                                      \
    _Pragma("unroll")                                                             \
    for (int n = 0; n < 4; ++n)                                                   \
      Bf[PB][n] = *(const bf16x8*)&B_s[((((TAP) * 8 + wn * 4 + n) * 4 + kg) * 16  \
                                        + lr) * 8];                               \
    _Pragma("unroll")                                                             \
    for (int m = 0; m < 4; ++m) {                                                 \
      int pb = wm * 64 + m * 16;                                                  \
      int px = ((pb >> 5) + ky) * 34 + (pb & 31) + lr + kx;                       \
      Af[PB][m] = *(const bf16x8*)&As[(px * 4 + ((kg ^ (px >> 1)) & 3)) * 8];     \
    }                                                                             \
  }
#define ROI_MMA(PB)                                                               \
  {                                                                               \
    _Pragma("unroll")                                                             \
    for (int m = 0; m < 4; ++m)                                                   \
      _Pragma("unroll")                                                           \
      for (int n = 0; n < 4; ++n)                                                 \
        acc[m][n] = __builtin_amdgcn_mfma_f32_16x16x32_bf16(Af[PB][m], Bf[PB][n], \
                                                            acc[m][n], 0, 0, 0);  \
  }
#define ROI_REGION(T0, T1)                                                        \
  {                                                                               \
    ROI_LOADF(0, T0);                                                             \
    _Pragma("unroll")                                                             \
    for (int tp = (T0); tp < (T1); ++tp) {                                        \
      if (tp + 1 < (T1)) { ROI_LOADF((tp + 1) & 1, tp + 1); }                     \
      ROI_MMA(tp & 1);                                                            \
    }                                                                             \
  }

  ROI_ISSUE_H1(0);
  ROI_ISSUE_A(0);
  __syncthreads();

  for (int kc = 0; kc < 7; ++kc) {
    int buf = kc & 1;
    const short* As = A_s[buf];
    ROI_ISSUE_H2(kc);
    ROI_ISSUE_A(buf ^ 1);
    __builtin_amdgcn_s_setprio(1);
    ROI_REGION(0, 5);
    __builtin_amdgcn_s_setprio(0);
    CBAR(2);
    ROI_ISSUE_H1(kc + 1);
    __builtin_amdgcn_s_setprio(1);
    ROI_REGION(5, 9);
    __builtin_amdgcn_s_setprio(0);
    CBAR(0);
  }
  {
    const short* As = A_s[1];
    ROI_ISSUE_H2(7);
    __builtin_amdgcn_s_setprio(1);
    ROI_REGION(0, 5);
    __builtin_amdgcn_s_setprio(0);
    CBAR(0);
    __builtin_amdgcn_s_setprio(1);
    ROI_REGION(5, 9);
    __builtin_amdgcn_s_setprio(0);
  }
#pragma unroll
  for (int m = 0; m < 4; ++m)
#pragma unroll
    for (int r = 0; r < 4; ++r) {
      int p = wm * 64 + m * 16 + kg * 4 + r;
      int y = yt * 8 + (p >> 5), x = p & 31;
      float* dst = part + (size_t)ks * 2097152 + (((size_t)b * 32 + y) * 32 + x) * 256
                        + nb * 128 + wn * 64 + lr;
#pragma unroll
      for (int n = 0; n < 4; ++n) dst[n * 16] = acc[m][n][r];
    }
}

// ---------------- per-pixel classifier MLP (4 pixels/block) ----------------
__global__ __launch_bounds__(256) void k_mlp(
    const float* __restrict__ part, const float* __restrict__ conv_b,
    const float* __restrict__ cw1, const float* __restrict__ cb1,
    const float* __restrict__ cw2, const float* __restrict__ cb2,
    float* __restrict__ logits) {
  __shared__ float v[1024];
  __shared__ float h[1024];
  int t = threadIdx.x;
  size_t base = (size_t)blockIdx.x * 1024;
  const size_t CH = (size_t)8192 * 256;
  for (int e = t; e < 1024; e += 256) {
    float s = part[base + e] + part[CH + base + e] +
              part[2 * CH + base + e] + part[3 * CH + base + e];
    v[e] = s + conv_b[e & 255];
  }
  __syncthreads();
  float a0 = cb1[t], a1 = a0, a2 = a0, a3 = a0;
  for (int k = 0; k < 256; ++k) {
    float w = cw1[k * 256 + t];
    a0 = fmaf(v[k], w, a0);
    a1 = fmaf(v[256 + k], w, a1);
    a2 = fmaf(v[512 + k], w, a2);
    a3 = fmaf(v[768 + k], w, a3);
  }
  h[t]       = fmaxf(a0, 0.f);
  h[256 + t] = fmaxf(a1, 0.f);
  h[512 + t] = fmaxf(a2, 0.f);
  h[768 + t] = fmaxf(a3, 0.f);
  __syncthreads();
  if (t < 24) {
    int pos = t / 6, c = t - 6 * pos;
    float acc = cb2[c];
    const float* hp = h + pos * 256;
    for (int k = 0; k < 256; ++k) acc = fmaf(hp[k], cw2[k * 6 + c], acc);
    logits[((size_t)blockIdx.x * 4 + pos) * 6 + c] = acc;
  }
}

// ---------------- mask head v9 (best): M8N4 ky-split + hoisted-B long-MFMA --------
// 512 blocks x 512 thr; block = 2 rows x 128 cols x 256 co; waves 2M(row) x 4N(64co)
__global__ __launch_bounds__(512, 2) void k_mask_mfma(
    const uint4* __restrict__ bfA, const short* __restrict__ wTm,
    const float* __restrict__ mb1,
    const float* __restrict__ bn_g, const float* __restrict__ bn_b,
    const float* __restrict__ bn_m, const float* __restrict__ bn_v,
    const float* __restrict__ mw2, float* __restrict__ m2p) {
  __shared__ __align__(16) short A_s[2][1040 * 8];   // 2 x 16640B: [2 rows][130][32ci]
  __shared__ __align__(16) short B_s[2][3072 * 8];   // 2 x 49152B: [3 kx][cog16][kg][lr]
  int t = threadIdx.x;
  int lane = t & 63, wv = t >> 6;
  int wm = wv >> 2, wn = wv & 3;
  int kg = lane >> 4, lr = lane & 15;
  int bid = blockIdx.x;
  int b = bid >> 6, yt = bid & 63;

  f32x4 acc[8][4];
#pragma unroll
  for (int m = 0; m < 8; ++m)
#pragma unroll
    for (int n = 0; n < 4; ++n) acc[m][n] = {0.f, 0.f, 0.f, 0.f};

  int ybase[3], cxoff[3], aldst[3];
  bool aok[3];
#pragma unroll
  for (int j = 0; j < 3; ++j) {
    int c = j * 512 + t;
    bool on = c < 1040;
    int cc = on ? c : 0;
    int pxi = cc >> 2, slot = cc & 3;
    int r = pxi / 130;
    int sx = pxi - r * 130;
    int x = sx - 1;
    int cg4 = slot ^ ((pxi >> 1) & 3);
    aok[j] = on && (x >= 0) && (x < 128);
    ybase[j] = 2 * yt + r - 1;
    cxoff[j] = cg4 * 16384 + x;
    aldst[j] = cc * 8;
  }
  int akc = (b * 32) << 14;

#define MSK_ISSUE_A(BUF, KYV, AKC)                                 \
  {                                                                \
    _Pragma("unroll")                                              \
    for (int j = 0; j < 3; ++j) {                                  \
      int y = ybase[j] + (KYV);                                    \
      bool ok = aok[j] && ((unsigned)y < 128u);                    \
      int off = ok ? ((AKC) + cxoff[j] + y * 128) : -1;            \
      if (j < 2 || t < 16) gld16(bfA + off, &A_s[BUF][aldst[j]]);  \
    }                                                              \
  }
#define MSK_ISSUE_B(BUF, BSRC)                                     \
  {                                                                \
    _Pragma("unroll")                                              \
    for (int j = 0; j < 6; ++j) {                                  \
      int idx = j * 512 + t;                                       \
      gld16((BSRC) + idx * 8, &B_s[BUF][idx * 8]);                 \
    }                                                              \
  }

// hoisted-B schedule: 12 B frags once, A 2-deep by m, 12-MFMA runs
#define MSK_COMPUTE(BUF)                                                          \
  {                                                                               \
    const short* As = A_s[BUF];                                                   \
    const short* Bs = B_s[BUF];                                                   \
    bf16x8 Bf[3][4];                                                              \
    _Pragma("unroll")                                                             \
    for (int kx = 0; kx < 3; ++kx)                                                \
      _Pragma("unroll")                                                           \
      for (int n = 0; n < 4; ++n)                                                 \
        Bf[kx][n] = *(const bf16x8*)&Bs[(((kx * 16 + wn * 4 + n) * 4 + kg) * 16   \
                                         + lr) * 8];                              \
    bf16x8 Afp[2][3];                                                             \
    _Pragma("unroll")                                                             \
    for (int kx = 0; kx < 3; ++kx) {                                              \
      int px = wm * 130 + lr + kx;                                                \
      Afp[0][kx] = *(const bf16x8*)&As[(px * 4 + ((kg ^ (px >> 1)) & 3)) * 8];    \
    }                                                                             \
    _Pragma("unroll")                                                             \
    for (int m = 0; m < 8; ++m) {                                                 \
      if (m + 1 < 8) {                                                            \
        _Pragma("unroll")                                                         \
        for (int kx = 0; kx < 3; ++kx) {                                          \
          int px = wm * 130 + (m + 1) * 16 + lr + kx;                             \
          Afp[(m + 1) & 1][kx] =                                                  \
              *(const bf16x8*)&As[(px * 4 + ((kg ^ (px >> 1)) & 3)) * 8];         \
        }                                                                         \
      }                                                                           \
      _Pragma("unroll")                                                           \
      for (int kx = 0; kx < 3; ++kx)                                              \
        _Pragma("unroll")                                                         \
        for (int n = 0; n < 4; ++n)                                               \
          acc[m][n] = __builtin_amdgcn_mfma_f32_16x16x32_bf16(                    \
              Afp[m & 1][kx], Bf[kx][n], acc[m][n], 0, 0, 0);                     \
    }                                                                             \
  }

  MSK_ISSUE_A(0, 0, akc);
  MSK_ISSUE_B(0, wTm);
  CBAR(0);

  int kyv = 0;
  const short* bnext = wTm + 24576;
  for (int s = 0; s < 24; ++s) {
    int buf = s & 1;
    if (s < 23) {
      int nky = (kyv == 2) ? 0 : kyv + 1;
      int nakc = (kyv == 2) ? akc + 65536 : akc;
      MSK_ISSUE_A(buf ^ 1, nky, nakc);
      MSK_ISSUE_B(buf ^ 1, bnext);
      kyv = nky;
      akc = nakc;
      bnext += 24576;
    }
    __builtin_amdgcn_s_setprio(1);
    MSK_COMPUTE(buf);
    __builtin_amdgcn_s_setprio(0);
    CBAR(0);
  }

  // epilogue: bias + BN + ReLU + 1x1, full 256-co in-block reduction
  float sc[4], sh[4], w2v[4], b1[4];
#pragma unroll
  for (int n = 0; n < 4; ++n) {
    int co = wn * 64 + n * 16 + lr;
    float s = bn_g[co] * rsqrtf(bn_v[co] + 1e-5f);
    sc[n] = s;
    sh[n] = bn_b[co] - bn_m[co] * s;
    b1[n] = mb1[co];
    w2v[n] = mw2[co];
  }
  float* red = (float*)&B_s[0][0];   // [2 wm][128 px][66 pad] f32 = 67584B
#pragma unroll
  for (int m = 0; m < 8; ++m)
#pragma unroll
    for (int r = 0; r < 4; ++r) {
      int px = m * 16 + kg * 4 + r;
      float s = 0.f;
#pragma unroll
      for (int n = 0; n < 4; ++n) {
        float z = fmaf(acc[m][n][r] + b1[n], sc[n], sh[n]);
        s = fmaf(w2v[n], fmaxf(z, 0.f), s);
      }
      red[(wm * 128 + px) * 66 + wn * 16 + lr] = s;
    }
  __syncthreads();
  if (t < 256) {
    float s = 0.f;
#pragma unroll
    for (int q = 0; q < 64; ++q) s += red[t * 66 + q];
    int row = 2 * yt + (t >> 7);
    int col = t & 127;
    m2p[((size_t)b * 128 + row) * 128 + col] = s;
  }
}

// ---------------- resize 130x130 -> 512x512 (interior + mb2) ----------------
__global__ __launch_bounds__(256) void k_resize(const float* __restrict__ m2p,
                                                const float* __restrict__ mb2,
                                                float* __restrict__ masks) {
  int idx = blockIdx.x * 256 + threadIdx.x;
  int b = idx >> 18;
  int rem = idx & 262143;
  int y = rem >> 9;
  int x = rem & 511;
  const float SC = 129.0f / 511.0f;
  float sy = (float)y * SC;
  float sx = (float)x * SC;
  float y0f = floorf(sy), x0f = floorf(sx);
  int y0 = (int)y0f, x0 = (int)x0f;
  int y1 = min(y0 + 1, 129), x1 = min(x0 + 1, 129);
  float wy = sy - y0f, wx = sx - x0f;
  float base = mb2[0];
  const float* p0 = m2p + (size_t)b * 16384;

  auto corner = [&](int yy, int xx) -> float {
    if (yy >= 1 && yy <= 128 && xx >= 1 && xx <= 128)
      return base + p0[(yy - 1) * 128 + (xx - 1)];
    return base;
  };
  float tv = corner(y0, x0) * (1.f - wx) + corner(y0, x1) * wx;
  float bv = corner(y1, x0) * (1.f - wx) + corner(y1, x1) * wx;
  masks[idx] = tv * (1.f - wy) + bv * wy;
}

extern "C" void kernel_launch(void* const* d_in, const int* in_sizes, int n_in,
                              void* d_out, int out_size, void* d_ws, size_t ws_size,
                              hipStream_t stream) {
  (void)in_sizes; (void)n_in; (void)out_size; (void)ws_size;
  const float* f0        = (const float*)d_in[1];
  const float* f1        = (const float*)d_in[2];
  const float* f2        = (const float*)d_in[3];
  const float* f3        = (const float*)d_in[4];
  const float* mask_feat = (const float*)d_in[5];
  const float* o         = (const float*)d_in[6];
  const float* dw1       = (const float*)d_in[7];
  const float* db1       = (const float*)d_in[8];
  const float* dw2       = (const float*)d_in[9];
  const float* db2       = (const float*)d_in[10];
  const float* cw1       = (const float*)d_in[11];
  const float* cb1       = (const float*)d_in[12];
  const float* cw2       = (const float*)d_in[13];
  const float* cb2       = (const float*)d_in[14];
  const float* conv_w    = (const float*)d_in[15];
  const float* conv_b    = (const float*)d_in[16];
  const float* mw1       = (const float*)d_in[17];
  const float* mb1       = (const float*)d_in[18];
  const float* bn_g      = (const float*)d_in[19];
  const float* bn_b      = (const float*)d_in[20];
  const float* bn_m      = (const float*)d_in[21];
  const float* bn_v      = (const float*)d_in[22];
  const float* mw2       = (const float*)d_in[23];
  const float* mb2       = (const float*)d_in[24];

  float* ws   = (float*)d_ws;
  uint4* bf   = (uint4*)(ws + 4);
  float* part = ws + PART_OFF;
  short* wTr  = (short*)(ws + WT_OFF);
  short* wTm  = wTr + WTR_SH;
  float* m2p  = ws + M2P_OFF;

  float* out_prop   = (float*)d_out;
  float* out_logits = out_prop + (size_t)8 * 1024 * 2;
  float* out_masks  = out_logits + (size_t)8 * 1024 * 6;

  hipLaunchKernelGGL(k_prep_w, dim3(640), dim3(256), 0, stream,
                     conv_w, mw1, wTr, wTm, ws);
  hipLaunchKernelGGL(k_prop, dim3(512), dim3(256), 0, stream,
                     o, dw1, db1, dw2, db2, out_prop);
  hipLaunchKernelGGL(k_sample, dim3(32, 4, 8), dim3(256), 0, stream,
                     f0, f1, f2, f3, out_prop, bf);
  hipLaunchKernelGGL(k_roi_mfma, dim3(256), dim3(512), 0, stream,
                     bf, wTr, part);
  hipLaunchKernelGGL(k_mlp, dim3(2048), dim3(256), 0, stream,
                     part, conv_b, cw1, cb1, cw2, cb2, out_logits);
  hipLaunchKernelGGL(k_cvt, dim3(16384), dim3(256), 0, stream,
                     mask_feat, bf);
  hipLaunchKernelGGL(k_mask_mfma, dim3(512), dim3(512), 0, stream,
                     bf, wTm, mb1, bn_g, bn_b, bn_m, bn_v, mw2, m2p);
  hipLaunchKernelGGL(k_resize, dim3(8192), dim3(256), 0, stream,
                     m2p, mb2, out_masks);
}